// Round 1
// baseline (118.647 us; speedup 1.0000x reference)
//
#include <hip/hip_runtime.h>
#include <math.h>

#define Bb 2
#define Nn 2048
#define Hh 256
#define NH 8
#define HD 32
#define NEDGE 65536
#define LN_EPS 1e-5f
#define MW 64          // mask words per row = N/32

typedef __bf16 bf16_t;
typedef bf16_t bf16x8 __attribute__((ext_vector_type(8)));
typedef bf16_t bf16x4 __attribute__((ext_vector_type(4)));
typedef float f32x4 __attribute__((ext_vector_type(4)));

__global__ void build_mask_kernel(const int* __restrict__ ei, unsigned int* __restrict__ mask) {
    int e = blockIdx.x * blockDim.x + threadIdx.x;
    if (e >= NEDGE) return;
    int src = ei[e];
    int dst = ei[NEDGE + e];
    atomicOr(&mask[src * MW + (dst >> 5)], 1u << (dst & 31));
}

// ---------------------------------------------------------------------------
// bf16 MFMA GEMM: 64x64 tile, BK=64, 4 waves 2x2. Reads fp32 x and fp32 W
// directly; converts to bf16 in the staging path (identical RNE rounding to
// the old cvt_zero pre-pass). Q stored fp32; K,V bf16.
// ---------------------------------------------------------------------------
#define LDA2 72

__global__ __launch_bounds__(256) void qkv_gemm3_kernel(
    const float* __restrict__ x,
    const float* __restrict__ Wq, const float* __restrict__ Wk, const float* __restrict__ Wv,
    float* __restrict__ Qb, bf16_t* __restrict__ Kb16, bf16_t* __restrict__ Vb16)
{
    __shared__ bf16_t As[64 * LDA2];
    __shared__ bf16_t Ws[64 * LDA2];
    int t = threadIdx.x;
    int lane = t & 63, w = t >> 6;
    int wm = w & 1, wn = w >> 1;
    int ml = lane & 15, quad = lane >> 4;
    int m0 = blockIdx.x * 64;
    int wsel = blockIdx.y >> 2;
    const float* W = (wsel == 0) ? Wq : ((wsel == 1) ? Wk : Wv);
    int n0 = (blockIdx.y & 3) * 64;
    int srow = t >> 3;
    int scol = (t & 7) * 8;
    f32x4 acc[2][2];
    f32x4 zero = {0.f, 0.f, 0.f, 0.f};
    acc[0][0] = zero; acc[0][1] = zero; acc[1][0] = zero; acc[1][1] = zero;

    for (int k0 = 0; k0 < Hh; k0 += 64) {
        float4 a[2][2], bwt[2][2];
        #pragma unroll
        for (int s = 0; s < 2; ++s) {
            const float* ap = x + (size_t)(m0 + srow + s * 32) * Hh + k0 + scol;
            a[s][0] = *(const float4*)ap;
            a[s][1] = *(const float4*)(ap + 4);
            const float* bp = W + (size_t)(n0 + srow + s * 32) * Hh + k0 + scol;
            bwt[s][0] = *(const float4*)bp;
            bwt[s][1] = *(const float4*)(bp + 4);
        }
        __syncthreads();
        #pragma unroll
        for (int s = 0; s < 2; ++s) {
            bf16x8 av = {(bf16_t)a[s][0].x, (bf16_t)a[s][0].y, (bf16_t)a[s][0].z, (bf16_t)a[s][0].w,
                         (bf16_t)a[s][1].x, (bf16_t)a[s][1].y, (bf16_t)a[s][1].z, (bf16_t)a[s][1].w};
            bf16x8 bv = {(bf16_t)bwt[s][0].x, (bf16_t)bwt[s][0].y, (bf16_t)bwt[s][0].z, (bf16_t)bwt[s][0].w,
                         (bf16_t)bwt[s][1].x, (bf16_t)bwt[s][1].y, (bf16_t)bwt[s][1].z, (bf16_t)bwt[s][1].w};
            *(bf16x8*)&As[(srow + s * 32) * LDA2 + scol] = av;
            *(bf16x8*)&Ws[(srow + s * 32) * LDA2 + scol] = bv;
        }
        __syncthreads();
        #pragma unroll
        for (int kk = 0; kk < 64; kk += 32) {
            bf16x8 af[2], bfr[2];
            #pragma unroll
            for (int i = 0; i < 2; ++i) {
                af[i]  = *(const bf16x8*)&As[(wm * 32 + i * 16 + ml) * LDA2 + kk + quad * 8];
                bfr[i] = *(const bf16x8*)&Ws[(wn * 32 + i * 16 + ml) * LDA2 + kk + quad * 8];
            }
            #pragma unroll
            for (int i = 0; i < 2; ++i)
                #pragma unroll
                for (int j = 0; j < 2; ++j)
                    acc[i][j] = __builtin_amdgcn_mfma_f32_16x16x32_bf16(af[i], bfr[j], acc[i][j], 0, 0, 0);
        }
    }
    bf16_t* Ob16 = (wsel == 1) ? Kb16 : Vb16;
    #pragma unroll
    for (int i = 0; i < 2; ++i)
        #pragma unroll
        for (int j = 0; j < 2; ++j)
            #pragma unroll
            for (int r = 0; r < 4; ++r) {
                int mg = m0 + wm * 32 + i * 16 + quad * 4 + r;
                int ng = n0 + wn * 32 + j * 16 + ml;
                float v = acc[i][j][r];
                if (wsel == 0) Qb[(size_t)mg * Hh + ng] = v;
                else           Ob16[(size_t)mg * Hh + ng] = (bf16_t)v;
            }
}

// ---------------------------------------------------------------------------
// Sparse attention v6: block per graph row i, BOTH batches per block.
// Mask decode once per row (was twice). 2048 blocks = exactly one residency
// pass (8 blocks/CU x 4 waves = 32 waves/CU). Per chunk: score phase
// (wave-per-K-row, bf16x4/lane), online softmax, V accumulation - all
// doubled over b in registers, barriers amortized over 2x work.
// ---------------------------------------------------------------------------
__global__ __launch_bounds__(256) void attn6_kernel(
    const float* __restrict__ Qb, const bf16_t* __restrict__ Kb16, const bf16_t* __restrict__ Vb16,
    const unsigned int* __restrict__ mask, float* __restrict__ attnb)
{
    __shared__ unsigned short nbr[Nn];   // 4 KB (worst case full row)
    __shared__ float qs[2][Hh];          // 2 KB
    __shared__ float sraw[2][32 * 9];    // 2.25 KB
    __shared__ float scw[2][Hh];         // 2 KB
    __shared__ float alpha_l[2][NH];
    __shared__ float linv_l[2][NH];
    __shared__ float obuf[4][Hh];        // 4 KB
    __shared__ int nn_sh;
    int i = blockIdx.x;
    int t = threadIdx.x;
    int h = t >> 5, dl = t & 31;
    int w = t >> 6, lane = t & 63;
    int hw = lane >> 3;                  // head owning cols 4*lane..4*lane+3

    if (t < 64) {   // wave 0: extract dedup'd neighbor list from bitmask
        unsigned int bits = mask[i * MW + t];
        int cnt = __popc(bits);
        int incl = cnt;
        #pragma unroll
        for (int off = 1; off < 64; off <<= 1) {
            int v = __shfl_up(incl, off, 64);
            if (t >= off) incl += v;
        }
        int idx = incl - cnt;
        unsigned int bb = bits;
        while (bb) {
            int bit = __ffs(bb) - 1;
            nbr[idx++] = (unsigned short)(t * 32 + bit);
            bb &= bb - 1;
        }
        if (t == 63) nn_sh = incl;
    }
    qs[0][t] = Qb[(size_t)i * Hh + t];
    qs[1][t] = Qb[(size_t)(Nn + i) * Hh + t];
    __syncthreads();
    int nn = nn_sh;

    float m_run[2] = {-1e30f, -1e30f};
    float l_run[2] = {0.f, 0.f};
    float o[2][4] = {{0.f, 0.f, 0.f, 0.f}, {0.f, 0.f, 0.f, 0.f}};
    const float scale = 0.17677669529663687f;  // 1/sqrt(32)
    int nch = (nn + 31) >> 5;
    for (int c = 0; c < nch; ++c) {
        int base = c << 5;
        int lim = min(32, nn - base);
        // ---- scores: wave w rows w, w+4, ...; lane covers dims 4l..4l+3 ----
        #pragma unroll
        for (int b = 0; b < 2; ++b) {
            float4 qv = *(const float4*)&qs[b][lane << 2];
            #pragma unroll
            for (int s = 0; s < 8; ++s) {
                int r = (s << 2) + w;
                if (r < lim) {
                    int j = nbr[base + r];
                    bf16x4 kv = *(const bf16x4*)(Kb16 + (((size_t)((b << 11) + j)) << 8) + (lane << 2));
                    float p = fmaf((float)kv.x, qv.x, fmaf((float)kv.y, qv.y,
                              fmaf((float)kv.z, qv.z, (float)kv.w * qv.w)));
                    p += __shfl_xor(p, 1, 64);
                    p += __shfl_xor(p, 2, 64);
                    p += __shfl_xor(p, 4, 64);
                    if ((lane & 7) == 0) sraw[b][r * 9 + (lane >> 3)] = p * scale;
                }
            }
        }
        __syncthreads();
        // ---- softmax in (h,dl) layout, both batches ----
        #pragma unroll
        for (int b = 0; b < 2; ++b) {
            float s_val = (dl < lim) ? sraw[b][dl * 9 + h] : -1e30f;
            float mc = s_val;
            #pragma unroll
            for (int m = 1; m < 32; m <<= 1) mc = fmaxf(mc, __shfl_xor(mc, m, 64));
            float m_new = fmaxf(m_run[b], mc);
            float wgt = __expf(s_val - m_new);
            float sum = wgt;
            #pragma unroll
            for (int m = 1; m < 32; m <<= 1) sum += __shfl_xor(sum, m, 64);
            float alpha = __expf(m_run[b] - m_new);
            l_run[b] = l_run[b] * alpha + sum;
            m_run[b] = m_new;
            scw[b][t] = wgt;
            if (dl == 0) alpha_l[b][h] = alpha;
        }
        __syncthreads();
        // ---- V phase: wave w rows w, w+4, ...; thread covers 4 cols ----
        #pragma unroll
        for (int b = 0; b < 2; ++b) {
            float av = alpha_l[b][hw];
            o[b][0] *= av; o[b][1] *= av; o[b][2] *= av; o[b][3] *= av;
            #pragma unroll
            for (int s = 0; s < 8; ++s) {
                int r = (s << 2) + w;
                if (r < lim) {
                    int j = nbr[base + r];
                    float wg = scw[b][(hw << 5) + r];
                    bf16x4 vv = *(const bf16x4*)(Vb16 + (((size_t)((b << 11) + j)) << 8) + (lane << 2));
                    o[b][0] = fmaf(wg, (float)vv.x, o[b][0]);
                    o[b][1] = fmaf(wg, (float)vv.y, o[b][1]);
                    o[b][2] = fmaf(wg, (float)vv.z, o[b][2]);
                    o[b][3] = fmaf(wg, (float)vv.w, o[b][3]);
                }
            }
        }
    }
    if (dl == 0) {
        linv_l[0][h] = (l_run[0] > 0.f) ? 1.f / l_run[0] : 0.f;
        linv_l[1][h] = (l_run[1] > 0.f) ? 1.f / l_run[1] : 0.f;
    }
    #pragma unroll
    for (int b = 0; b < 2; ++b) {
        __syncthreads();   // b=0: linv visible; b=1: prev obuf reads done
        obuf[w][(lane << 2) + 0] = o[b][0];
        obuf[w][(lane << 2) + 1] = o[b][1];
        obuf[w][(lane << 2) + 2] = o[b][2];
        obuf[w][(lane << 2) + 3] = o[b][3];
        __syncthreads();
        float val = obuf[0][t] + obuf[1][t] + obuf[2][t] + obuf[3][t];
        attnb[(((size_t)((b << 11) + i)) << 8) + t] = val * linv_l[b][t >> 5];
    }
}

// ---------------------------------------------------------------------------
// out = LayerNorm(attn @ Wo^T + x): 16 full rows per block, fp32 Wo read
// directly and converted to bf16 in the staging path.
// ---------------------------------------------------------------------------
__global__ __launch_bounds__(256) void out_ln_kernel(
    const float* __restrict__ attnb, const float* __restrict__ Wo,
    const float* __restrict__ x, const float* __restrict__ gamma,
    const float* __restrict__ beta, float* __restrict__ out)
{
    __shared__ bf16_t As[16 * LDA2];
    __shared__ __align__(16) char wbuf[256 * LDA2 * sizeof(bf16_t)];  // 36.9 KB
    bf16_t* Ws = (bf16_t*)wbuf;
    float* yb = (float*)wbuf;          // 16 x 260 fp32, aliased after use
    int t = threadIdx.x;
    int lane = t & 63, w = t >> 6;
    int ml = lane & 15, quad = lane >> 4;
    int m0 = blockIdx.x * 16;
    f32x4 acc[4];
    f32x4 zero = {0.f, 0.f, 0.f, 0.f};
    acc[0] = zero; acc[1] = zero; acc[2] = zero; acc[3] = zero;
    int arow = t >> 4, acol = (t & 15) * 4;
    int wrow = t >> 3, wcol = (t & 7) * 8;

    for (int k0 = 0; k0 < Hh; k0 += 64) {
        float4 av = *(const float4*)(attnb + (size_t)(m0 + arow) * Hh + k0 + acol);
        float4 wva[8], wvb[8];
        #pragma unroll
        for (int s = 0; s < 8; ++s) {
            const float* wp = Wo + (size_t)(wrow + s * 32) * Hh + k0 + wcol;
            wva[s] = *(const float4*)wp;
            wvb[s] = *(const float4*)(wp + 4);
        }
        __syncthreads();
        bf16x4 ac = {(bf16_t)av.x, (bf16_t)av.y, (bf16_t)av.z, (bf16_t)av.w};
        *(bf16x4*)&As[arow * LDA2 + acol] = ac;
        #pragma unroll
        for (int s = 0; s < 8; ++s) {
            bf16x8 wv8 = {(bf16_t)wva[s].x, (bf16_t)wva[s].y, (bf16_t)wva[s].z, (bf16_t)wva[s].w,
                          (bf16_t)wvb[s].x, (bf16_t)wvb[s].y, (bf16_t)wvb[s].z, (bf16_t)wvb[s].w};
            *(bf16x8*)&Ws[(wrow + s * 32) * LDA2 + wcol] = wv8;
        }
        __syncthreads();
        #pragma unroll
        for (int kk = 0; kk < 64; kk += 32) {
            bf16x8 af = *(const bf16x8*)&As[ml * LDA2 + kk + quad * 8];
            #pragma unroll
            for (int ct = 0; ct < 4; ++ct) {
                bf16x8 bfr = *(const bf16x8*)&Ws[(w * 64 + ct * 16 + ml) * LDA2 + kk + quad * 8];
                acc[ct] = __builtin_amdgcn_mfma_f32_16x16x32_bf16(af, bfr, acc[ct], 0, 0, 0);
            }
        }
    }
    __syncthreads();   // all Ws reads done before aliasing as yb
    #pragma unroll
    for (int ct = 0; ct < 4; ++ct)
        #pragma unroll
        for (int r = 0; r < 4; ++r) {
            int row = quad * 4 + r;
            int col = w * 64 + ct * 16 + ml;
            yb[row * 260 + col] = acc[ct][r] + x[(size_t)(m0 + row) * Hh + col];
        }
    __syncthreads();
    for (int rr = 0; rr < 4; ++rr) {
        int row = w * 4 + rr;
        float4 v = *(const float4*)&yb[row * 260 + lane * 4];
        float sum = v.x + v.y + v.z + v.w;
        #pragma unroll
        for (int m = 1; m < 64; m <<= 1) sum += __shfl_xor(sum, m, 64);
        float mu = sum * (1.f / Hh);
        float4 d = {v.x - mu, v.y - mu, v.z - mu, v.w - mu};
        float ss = d.x * d.x + d.y * d.y + d.z * d.z + d.w * d.w;
        #pragma unroll
        for (int m = 1; m < 64; m <<= 1) ss += __shfl_xor(ss, m, 64);
        float r = rsqrtf(ss * (1.f / Hh) + LN_EPS);
        float4 g  = *(const float4*)(gamma + lane * 4);
        float4 bt = *(const float4*)(beta + lane * 4);
        float4 ov = {d.x * r * g.x + bt.x, d.y * r * g.y + bt.y,
                     d.z * r * g.z + bt.z, d.w * r * g.w + bt.w};
        *(float4*)(out + (size_t)(m0 + row) * Hh + lane * 4) = ov;
    }
}

extern "C" void kernel_launch(void* const* d_in, const int* in_sizes, int n_in,
                              void* d_out, int out_size, void* d_ws, size_t ws_size,
                              hipStream_t stream) {
    const float* x     = (const float*)d_in[0];
    const int*   ei    = (const int*)d_in[1];
    // d_in[2] = edge_weights: unused by the reference
    const float* Wq    = (const float*)d_in[3];
    const float* Wk    = (const float*)d_in[4];
    const float* Wv    = (const float*)d_in[5];
    const float* Wo    = (const float*)d_in[6];
    const float* gamma = (const float*)d_in[7];
    const float* beta  = (const float*)d_in[8];
    float* out = (float*)d_out;

    const int NTOK = Bb * Nn * Hh;  // 1048576
    float*  Qb    = (float*)d_ws;
    bf16_t* Kb16  = (bf16_t*)(Qb + NTOK);
    bf16_t* Vb16  = Kb16 + NTOK;
    float*  attnb = (float*)(Vb16 + NTOK);
    unsigned int* mask = (unsigned int*)(attnb + NTOK);

    hipMemsetAsync(mask, 0, Nn * MW * sizeof(unsigned int), stream);
    hipLaunchKernelGGL(build_mask_kernel, dim3(NEDGE / 256), dim3(256), 0, stream, ei, mask);
    hipLaunchKernelGGL(qkv_gemm3_kernel, dim3((Bb * Nn) / 64, 12), dim3(256), 0, stream,
                       x, Wq, Wk, Wv, Qb, Kb16, Vb16);
    hipLaunchKernelGGL(attn6_kernel, dim3(Nn), dim3(256), 0, stream,
                       Qb, Kb16, Vb16, mask, attnb);
    hipLaunchKernelGGL(out_ln_kernel, dim3((Bb * Nn) / 16), dim3(256), 0, stream,
                       attnb, Wo, x, gamma, beta, out);
}